// Round 1
// baseline (243.776 us; speedup 1.0000x reference)
//
#include <hip/hip_runtime.h>
#include <math.h>

// Problem constants (B,S,D,H,HD) = (2,2048,1024,16,64)
#define CB 2
#define CS 2048
#define CD 1024
#define CH 16
#define CHD 64
#define CM (CB*CS)   // 4096 rows

#define QSCALE 0.18033688f   // 0.125 * log2(e)
#define LOG2E  1.44269504f
#define BLOG   40.0f         // static softmax bound (log2 domain)

typedef unsigned short u16;
using bf16x8 = __attribute__((ext_vector_type(8))) short;
using u16x8  = __attribute__((ext_vector_type(8))) unsigned short;
using f32x4  = __attribute__((ext_vector_type(4))) float;
using f32x16 = __attribute__((ext_vector_type(16))) float;
using u32x4  = __attribute__((ext_vector_type(4))) unsigned int;

__device__ __forceinline__ u16 f2bf(float f) {
    unsigned int u = __float_as_uint(f);
    u = (u + 0x7FFFu + ((u >> 16) & 1u)) >> 16;
    return (u16)u;
}

__device__ __forceinline__ unsigned cvt_pk_bf16(float lo, float hi) {
    unsigned r;
    asm("v_cvt_pk_bf16_f32 %0, %1, %2" : "=v"(r) : "v"(lo), "v"(hi));
    return r;
}

__device__ __forceinline__ void load_lds16(const u16* g, u16* l) {
    __builtin_amdgcn_global_load_lds(
        (const __attribute__((address_space(1))) unsigned int*)g,
        (__attribute__((address_space(3))) unsigned int*)l, 16, 0, 0);
}

// ---------------------------------------------------------------------------
__global__ __launch_bounds__(256)
void convert_x(const float* __restrict__ X, u16* __restrict__ Xb)
{
    size_t i = ((size_t)blockIdx.x * 256 + threadIdx.x) * 8;
    float4 v0 = *(const float4*)(X + i);
    float4 v1 = *(const float4*)(X + i + 4);
    u16x8 o;
    o[0] = f2bf(v0.x); o[1] = f2bf(v0.y); o[2] = f2bf(v0.z); o[3] = f2bf(v0.w);
    o[4] = f2bf(v1.x); o[5] = f2bf(v1.y); o[6] = f2bf(v1.z); o[7] = f2bf(v1.w);
    *(u16x8*)(Xb + i) = o;
}

// ---------------------------------------------------------------------------
// W [K][N] fp32 -> Wt [N][K] bf16 transposed; Wq pre-scaled by QSCALE.
// ---------------------------------------------------------------------------
__global__ __launch_bounds__(256)
void convert_wt(const float* __restrict__ Wq, const float* __restrict__ Wk,
                const float* __restrict__ Wv, u16* __restrict__ Wt)
{
    const int z = blockIdx.z;
    const float* W = (z == 0) ? Wq : (z == 1) ? Wk : Wv;
    const float sc = (z == 0) ? QSCALE : 1.0f;
    u16* Wo = Wt + (size_t)z * CD * CD;

    __shared__ u16 T[64][72];
    const int k0 = blockIdx.x << 6;
    const int n0 = blockIdx.y << 6;
    const int tid = threadIdx.x;

    #pragma unroll
    for (int it = 0; it < 4; ++it) {
        int r = (tid >> 4) + (it << 4);
        int c = (tid & 15) << 2;
        float4 v = *(const float4*)(W + (size_t)(k0 + r) * CD + n0 + c);
        T[c + 0][r] = f2bf(v.x * sc);
        T[c + 1][r] = f2bf(v.y * sc);
        T[c + 2][r] = f2bf(v.z * sc);
        T[c + 3][r] = f2bf(v.w * sc);
    }
    __syncthreads();
    #pragma unroll
    for (int it = 0; it < 2; ++it) {
        int cc = tid + (it << 8);
        int n  = cc >> 3;
        int ch = (cc & 7) << 3;
        *(uint4*)(Wo + (size_t)(n0 + n) * CD + k0 + ch) = *(const uint4*)&T[n][ch];
    }
}

// ---------------------------------------------------------------------------
// QKV GEMM (unchanged R6 form): bf16 MFMA 16x16x32, 128x128 tile, BK=64,
// global_load_lds staging with 8-slot XOR swizzle.  3 blocks/CU.
// z=0/1 -> Q/K bf16 [b,h,s,hd]; z=2 -> V bf16 transposed [b,h,hd,s].
// ---------------------------------------------------------------------------
__global__ __launch_bounds__(256, 3)
void qkv_gemm_mfma(const u16* __restrict__ Xb, const u16* __restrict__ Wt,
                   const float* __restrict__ bq, const float* __restrict__ bk,
                   const float* __restrict__ bv,
                   u16* __restrict__ Qb, u16* __restrict__ Kb,
                   u16* __restrict__ Vt)
{
    const int z = blockIdx.z;
    const u16* W = Wt + (size_t)z * CD * CD;
    const float* bias = (z == 0) ? bq : (z == 1) ? bk : bv;
    const float bscale = (z == 0) ? QSCALE : 1.0f;

    __shared__ u16 smem[16384];         // As [128][64] + Bs [128][64] = 32 KB
    u16* As = smem;
    u16* Bs = smem + 8192;

    const int tid  = threadIdx.x;
    const int w    = tid >> 6;
    const int l    = tid & 63;
    const int l15  = l & 15;
    const int quad = l >> 4;
    const int wm   = w >> 1;
    const int wn   = w & 1;

    const int row0 = blockIdx.x << 7;
    const int n0   = blockIdx.y << 7;

    f32x4 acc[4][4];
    #pragma unroll
    for (int mi = 0; mi < 4; ++mi)
        #pragma unroll
        for (int nt = 0; nt < 4; ++nt)
            acc[mi][nt] = (f32x4){0.f, 0.f, 0.f, 0.f};

    const u16* Ag = Xb + (size_t)row0 * CD;
    const u16* Bg = W  + (size_t)n0   * CD;
    const int lr8 = l >> 3;                 // row within 8-row group
    const int ls  = l & 7;                  // stored slot
    const int lg  = (ls ^ lr8) << 3;        // swizzled global chunk (u16)
    const int q7  = l15 & 7;

    for (int k0 = 0; k0 < CD; k0 += 64) {
        __syncthreads();
        #pragma unroll
        for (int i = 0; i < 4; ++i) {
            int r = w * 32 + 8 * i + lr8;
            load_lds16(Ag + (size_t)r * CD + k0 + lg, As + (size_t)(w * 32 + 8 * i) * 64);
            load_lds16(Bg + (size_t)r * CD + k0 + lg, Bs + (size_t)(w * 32 + 8 * i) * 64);
        }
        __syncthreads();

        #pragma unroll
        for (int kk = 0; kk < 2; ++kk) {
            bf16x8 af[4], bfr[4];
            #pragma unroll
            for (int mi = 0; mi < 4; ++mi)
                af[mi] = *(const bf16x8*)
                    &As[(wm * 64 + mi * 16 + l15) * 64 + (((kk * 4 + quad) ^ q7) << 3)];
            #pragma unroll
            for (int nt = 0; nt < 4; ++nt)
                bfr[nt] = *(const bf16x8*)
                    &Bs[(wn * 64 + nt * 16 + l15) * 64 + (((kk * 4 + quad) ^ q7) << 3)];
            #pragma unroll
            for (int mi = 0; mi < 4; ++mi)
                #pragma unroll
                for (int nt = 0; nt < 4; ++nt)
                    acc[mi][nt] = __builtin_amdgcn_mfma_f32_16x16x32_bf16(
                        af[mi], bfr[nt], acc[mi][nt], 0, 0, 0);
        }
    }

    __syncthreads();   // K-loop LDS reads done; smem reusable

    if (z < 2) {
        u16* Og = (z == 0) ? Qb : Kb;
        float bb[4];
        #pragma unroll
        for (int nt = 0; nt < 4; ++nt)
            bb[nt] = bias[n0 + wn * 64 + nt * 16 + l15] * bscale;

        u16 (*Ct)[136] = (u16(*)[136])smem;
        #pragma unroll
        for (int mh = 0; mh < 2; ++mh) {
            if (wm == mh) {
                #pragma unroll
                for (int nt = 0; nt < 4; ++nt)
                    #pragma unroll
                    for (int mi = 0; mi < 4; ++mi)
                        #pragma unroll
                        for (int r = 0; r < 4; ++r)
                            Ct[mi * 16 + quad * 4 + r][wn * 64 + nt * 16 + l15] =
                                f2bf(acc[mi][nt][r] + bb[nt]);
            }
            __syncthreads();
            #pragma unroll
            for (int it = 0; it < 4; ++it) {
                int c  = tid + (it << 8);
                int rl = c >> 4;
                int ck = c & 15;
                uint4 d = *(const uint4*)&Ct[rl][ck * 8];
                int gcol = n0 + ck * 8;
                int h = gcol >> 6, hd = gcol & 63;
                int m = row0 + mh * 64 + rl;
                int b = m >> 11, s = m & (CS - 1);
                *(uint4*)(Og + ((size_t)(b * CH + h) * CS + s) * CHD + hd) = d;
            }
            __syncthreads();
        }
    } else {
        u16 (*Ct)[136] = (u16(*)[136])smem;
        #pragma unroll
        for (int nh = 0; nh < 2; ++nh) {
            if (wn == nh) {
                #pragma unroll
                for (int nt = 0; nt < 4; ++nt) {
                    int col = n0 + nh * 64 + nt * 16 + l15;
                    float bb = bias[col];
                    #pragma unroll
                    for (int mi = 0; mi < 4; ++mi)
                        #pragma unroll
                        for (int r = 0; r < 4; ++r) {
                            int ml = wm * 64 + mi * 16 + quad * 4 + r;
                            Ct[nt * 16 + l15][ml] = f2bf(acc[mi][nt][r] + bb);
                        }
                }
            }
            __syncthreads();
            #pragma unroll
            for (int it = 0; it < 4; ++it) {
                int c   = tid + (it << 8);
                int dvl = c >> 4;
                int ch  = c & 15;
                uint4 vdat = *(const uint4*)&Ct[dvl][ch * 8];
                int col = n0 + nh * 64 + dvl;
                int h   = col >> 6;
                int dv  = col & 63;
                int m0  = row0 + ch * 8;
                int b   = m0 >> 11;
                int s0  = m0 & (CS - 1);
                *(uint4*)(Vt + (((size_t)(b * CH + h)) * CHD + dv) * CS + s0) = vdat;
            }
            __syncthreads();
        }
    }
}

// ---------------------------------------------------------------------------
// Flash attention v9: 32x32x16 MFMA, swapped QK^T (S^T: col = q = lane&31),
// softmax fully lane-local (static log2-domain bound), PV A-fragments built
// in-register via v_cvt_pk_bf16_f32 + one shfl_xor(32) + cndmask per dword
// pair -- P never touches LDS.  Freed 32 KB -> double-buffered K/V with
// stage-before-compute (one barrier per tile, vmcnt drain lands after
// compute).  Mask loads issued before the stage (vmcnt(4) wait, not a full
// drain).  8 waves = 4 q-groups x 2 key-halves, 2 blocks/CU (VGPR-capped).
// Bijective XCD swizzle: 64 consecutive blocks (4 heads) per XCD -> K/V
// L2-resident (2 MB < 4 MB).
// ---------------------------------------------------------------------------

#define ATTN_MLOAD(KT)                                                        \
    f32x4 mv[8];                                                              \
    _Pragma("unroll")                                                         \
    for (int st = 0; st < 2; ++st)                                            \
        _Pragma("unroll")                                                     \
        for (int g = 0; g < 4; ++g)                                           \
            mv[st * 4 + g] = *(const f32x4*)(mrh + ((KT) << 6) + st * 32 +    \
                                             g * 8 + hi * 4);

#define ATTN_STAGE(KT, KD, VD)                                                \
    {                                                                         \
        const int k0s = (KT) << 6;                                            \
        _Pragma("unroll")                                                     \
        for (int i = 0; i < 2; ++i) {                                         \
            const int rl = (qh << 4) + (i << 3);                              \
            load_lds16(Kph + (size_t)(k0s + rl + lr8) * CHD + lg, (KD) + rl * 64); \
            load_lds16(Vph + (size_t)(rl + lr8) * CS + k0s + lg,  (VD) + rl * 64); \
        }                                                                     \
    }

#define ATTN_TILE(KC, VC)                                                     \
    {                                                                         \
        _Pragma("unroll")                                                     \
        for (int st = 0; st < 2; ++st) {                                      \
            bf16x8 kf[4];                                                     \
            _Pragma("unroll")                                                 \
            for (int c = 0; c < 4; ++c)                                       \
                kf[c] = *(const bf16x8*)&(KC)[(st * 32 + l31) * 64 +          \
                            ((((c << 1) + hi) ^ sw7) << 3)];                  \
            f32x16 s;                                                         \
            _Pragma("unroll")                                                 \
            for (int g = 0; g < 4; ++g)                                       \
                _Pragma("unroll")                                             \
                for (int j = 0; j < 4; ++j)                                   \
                    s[g * 4 + j] = fmaf(mv[st * 4 + g][j], LOG2E, -BLOG);     \
            _Pragma("unroll")                                                 \
            for (int c = 0; c < 4; ++c)                                       \
                s = __builtin_amdgcn_mfma_f32_32x32x16_bf16(kf[c], qf[c], s,  \
                                                            0, 0, 0);         \
            _Pragma("unroll")                                                 \
            for (int r = 0; r < 16; ++r) s[r] = exp2f(s[r]);                  \
            lsum += ((s[0] + s[1]) + (s[2] + s[3])) +                         \
                    ((s[4] + s[5]) + (s[6] + s[7])) +                         \
                    ((s[8] + s[9]) + (s[10] + s[11])) +                       \
                    ((s[12] + s[13]) + (s[14] + s[15]));                      \
            _Pragma("unroll")                                                 \
            for (int cc = 0; cc < 2; ++cc) {                                  \
                unsigned px  = cvt_pk_bf16(s[8 * cc + 0], s[8 * cc + 1]);     \
                unsigned px2 = cvt_pk_bf16(s[8 * cc + 2], s[8 * cc + 3]);     \
                unsigned py  = cvt_pk_bf16(s[8 * cc + 4], s[8 * cc + 5]);     \
                unsigned py2 = cvt_pk_bf16(s[8 * cc + 6], s[8 * cc + 7]);     \
                unsigned t1  = __shfl_xor(hi ? px : py, 32);                  \
                unsigned t2  = __shfl_xor(hi ? px2 : py2, 32);                \
                union { u32x4 u; bf16x8 v; } pa;                              \
                pa.u[0] = hi ? t1 : px;                                       \
                pa.u[1] = hi ? t2 : px2;                                      \
                pa.u[2] = hi ? py : t1;                                       \
                pa.u[3] = hi ? py2 : t2;                                      \
                const int c = st * 2 + cc;                                    \
                bf16x8 vlo = *(const bf16x8*)&(VC)[l31 * 64 +                 \
                                 ((((c << 1) + hi) ^ sw7) << 3)];             \
                bf16x8 vhi = *(const bf16x8*)&(VC)[(32 + l31) * 64 +          \
                                 ((((c << 1) + hi) ^ sw7) << 3)];             \
                O0 = __builtin_amdgcn_mfma_f32_32x32x16_bf16(pa.v, vlo, O0,   \
                                                             0, 0, 0);        \
                O1 = __builtin_amdgcn_mfma_f32_32x32x16_bf16(pa.v, vhi, O1,   \
                                                             0, 0, 0);        \
            }                                                                 \
        }                                                                     \
    }

__global__ __launch_bounds__(512, 4)
void attn_mfma(const u16* __restrict__ Qg, const u16* __restrict__ Kg,
               const u16* __restrict__ Vtg, const float* __restrict__ mask,
               float* __restrict__ out)
{
    __shared__ u16 smem[32768];          // 64 KB

    // bijective XCD swizzle: 64 consecutive blocks (4 heads) per XCD
    const int flat = blockIdx.y * 16 + blockIdx.x;      // 512 blocks
    const int nf   = ((flat & 7) << 6) + (flat >> 3);
    const int q0   = (nf & 15) << 7;
    const int bh   = nf >> 4;
    const int b    = bh >> 4;
    const int h    = bh & 15;

    const int tid = threadIdx.x;
    const int w   = tid >> 6;            // 0..7
    const int qh  = w & 3;               // q-group (32 q)
    const int kh  = w >> 2;              // key half (1024 keys)
    const int l   = tid & 63;
    const int l31 = l & 31;
    const int hi  = l >> 5;
    const int lr8 = l >> 3;
    const int lg  = ((l & 7) ^ lr8) << 3;
    const int sw7 = l31 & 7;

    const u16* Qp    = Qg  + (size_t)bh * CS * CHD;
    const u16* Kph   = Kg  + ((size_t)bh * CS + (kh << 10)) * CHD;
    const u16* Vph   = Vtg + (size_t)bh * CHD * CS + (kh << 10);
    const float* mrh = mask + (size_t)b * CS + (kh << 10);

    // LDS: K dbuf [kh][2][64*64], V dbuf [kh][2][64*64]
    u16* K0 = smem + (kh << 13);
    u16* K1 = K0 + 4096;
    u16* V0 = smem + 16384 + (kh << 13);
    u16* V1 = V0 + 4096;

    // Q B-fragments (col = q = lane&31, 8 d-elems at hi*8 per 16-d chunk)
    bf16x8 qf[4];
    #pragma unroll
    for (int c = 0; c < 4; ++c)
        qf[c] = *(const bf16x8*)(
            Qp + (size_t)(q0 + qh * 32 + l31) * CHD + c * 16 + hi * 8);

    f32x16 O0, O1;
    #pragma unroll
    for (int r = 0; r < 16; ++r) { O0[r] = 0.f; O1[r] = 0.f; }
    float lsum = 0.f;

    ATTN_STAGE(0, K0, V0);
    __syncthreads();

    #pragma unroll 1
    for (int kt = 0; kt < 16; kt += 2) {
        {
            ATTN_MLOAD(kt);
            __builtin_amdgcn_sched_barrier(0);
            ATTN_STAGE(kt + 1, K1, V1);
            __builtin_amdgcn_sched_barrier(0);
            ATTN_TILE(K0, V0);
            __syncthreads();
        }
        {
            ATTN_MLOAD(kt + 1);
            __builtin_amdgcn_sched_barrier(0);
            if (kt + 2 < 16) ATTN_STAGE(kt + 2, K0, V0);
            __builtin_amdgcn_sched_barrier(0);
            ATTN_TILE(K1, V1);
            __syncthreads();
        }
    }

    // ---- combine k-halves (linear: static bound) ----
    const float lsf = lsum + __shfl_xor(lsum, 32);

    float* ob   = (float*)smem;               // 32 KB: [4 qh][32 q][64 dv]
    float* lbuf = (float*)(smem + 16384);     // 128 floats (V region dead)

    if (kh == 1) {
        float* obw = ob + (qh << 11);
        #pragma unroll
        for (int r = 0; r < 16; ++r) {
            const int ql = (r & 3) + ((r >> 2) << 3) + (hi << 2);
            obw[ql * 64 + l31]      = O0[r];
            obw[ql * 64 + 32 + l31] = O1[r];
        }
        if (hi == 0) lbuf[(qh << 5) + l31] = lsf;
    }
    __syncthreads();

    if (kh == 0) {
        const float inv = 1.0f / (lsf + lbuf[(qh << 5) + l31]);
        const float* obw = ob + (qh << 11);
        #pragma unroll
        for (int r = 0; r < 16; ++r) {
            const int ql   = (r & 3) + ((r >> 2) << 3) + (hi << 2);
            const float iv = __shfl(inv, ql);
            float* orow = out + ((size_t)b * CS + q0 + (qh << 5) + ql) * CD + h * CHD;
            orow[l31]      = (O0[r] + obw[ql * 64 + l31]) * iv;
            orow[32 + l31] = (O1[r] + obw[ql * 64 + 32 + l31]) * iv;
        }
    }
}

// ---------------------------------------------------------------------------
extern "C" void kernel_launch(void* const* d_in, const int* in_sizes, int n_in,
                              void* d_out, int out_size, void* d_ws, size_t ws_size,
                              hipStream_t stream)
{
    const float* X    = (const float*)d_in[0];
    const float* mask = (const float*)d_in[1];
    const float* Wq   = (const float*)d_in[2];
    const float* bq   = (const float*)d_in[3];
    const float* Wk   = (const float*)d_in[4];
    const float* bk   = (const float*)d_in[5];
    const float* Wv   = (const float*)d_in[6];
    const float* bv   = (const float*)d_in[7];
    float* out = (float*)d_out;

    char* ws = (char*)d_ws;
    u16* Xb = (u16*)(ws);
    u16* Wt = (u16*)(ws + ((size_t)8  << 20));
    u16* Qb = (u16*)(ws + ((size_t)14 << 20));
    u16* Kb = (u16*)(ws + ((size_t)22 << 20));
    u16* Vt = (u16*)(ws + ((size_t)30 << 20));

    convert_x<<<CM * CD / (256 * 8), 256, 0, stream>>>(X, Xb);
    convert_wt<<<dim3(16, 16, 3), 256, 0, stream>>>(Wq, Wk, Wv, Wt);
    qkv_gemm_mfma<<<dim3(CM / 128, CD / 128, 3), 256, 0, stream>>>(
        Xb, Wt, bq, bk, bv, Qb, Kb, Vt);
    attn_mfma<<<dim3(CS / 128, CB * CH), 512, 0, stream>>>(Qb, Kb, Vt, mask, out);
}

// Round 2
// 194.651 us; speedup vs baseline: 1.2524x; 1.2524x over previous
//
#include <hip/hip_runtime.h>
#include <math.h>

// Problem constants (B,S,D,H,HD) = (2,2048,1024,16,64)
#define CB 2
#define CS 2048
#define CD 1024
#define CH 16
#define CHD 64
#define CM (CB*CS)   // 4096 rows

#define QSCALE 0.18033688f   // 0.125 * log2(e)
#define LOG2E  1.44269504f
#define BLOG   40.0f         // static softmax bound (log2 domain)

typedef unsigned short u16;
using bf16x8 = __attribute__((ext_vector_type(8))) short;
using u16x8  = __attribute__((ext_vector_type(8))) unsigned short;
using f32x4  = __attribute__((ext_vector_type(4))) float;
using f32x16 = __attribute__((ext_vector_type(16))) float;
using u32x4  = __attribute__((ext_vector_type(4))) unsigned int;

__device__ __forceinline__ u16 f2bf(float f) {
    unsigned int u = __float_as_uint(f);
    u = (u + 0x7FFFu + ((u >> 16) & 1u)) >> 16;
    return (u16)u;
}

__device__ __forceinline__ unsigned cvt_pk_bf16(float lo, float hi) {
    unsigned r;
    asm("v_cvt_pk_bf16_f32 %0, %1, %2" : "=v"(r) : "v"(lo), "v"(hi));
    return r;
}

__device__ __forceinline__ void load_lds16(const u16* g, u16* l) {
    __builtin_amdgcn_global_load_lds(
        (const __attribute__((address_space(1))) unsigned int*)g,
        (__attribute__((address_space(3))) unsigned int*)l, 16, 0, 0);
}

// ---------------------------------------------------------------------------
__global__ __launch_bounds__(256)
void convert_x(const float* __restrict__ X, u16* __restrict__ Xb)
{
    size_t i = ((size_t)blockIdx.x * 256 + threadIdx.x) * 8;
    float4 v0 = *(const float4*)(X + i);
    float4 v1 = *(const float4*)(X + i + 4);
    u16x8 o;
    o[0] = f2bf(v0.x); o[1] = f2bf(v0.y); o[2] = f2bf(v0.z); o[3] = f2bf(v0.w);
    o[4] = f2bf(v1.x); o[5] = f2bf(v1.y); o[6] = f2bf(v1.z); o[7] = f2bf(v1.w);
    *(u16x8*)(Xb + i) = o;
}

// ---------------------------------------------------------------------------
// W [K][N] fp32 -> Wt [N][K] bf16 transposed; Wq pre-scaled by QSCALE.
// ---------------------------------------------------------------------------
__global__ __launch_bounds__(256)
void convert_wt(const float* __restrict__ Wq, const float* __restrict__ Wk,
                const float* __restrict__ Wv, u16* __restrict__ Wt)
{
    const int z = blockIdx.z;
    const float* W = (z == 0) ? Wq : (z == 1) ? Wk : Wv;
    const float sc = (z == 0) ? QSCALE : 1.0f;
    u16* Wo = Wt + (size_t)z * CD * CD;

    __shared__ u16 T[64][72];
    const int k0 = blockIdx.x << 6;
    const int n0 = blockIdx.y << 6;
    const int tid = threadIdx.x;

    #pragma unroll
    for (int it = 0; it < 4; ++it) {
        int r = (tid >> 4) + (it << 4);
        int c = (tid & 15) << 2;
        float4 v = *(const float4*)(W + (size_t)(k0 + r) * CD + n0 + c);
        T[c + 0][r] = f2bf(v.x * sc);
        T[c + 1][r] = f2bf(v.y * sc);
        T[c + 2][r] = f2bf(v.z * sc);
        T[c + 3][r] = f2bf(v.w * sc);
    }
    __syncthreads();
    #pragma unroll
    for (int it = 0; it < 2; ++it) {
        int cc = tid + (it << 8);
        int n  = cc >> 3;
        int ch = (cc & 7) << 3;
        *(uint4*)(Wo + (size_t)(n0 + n) * CD + k0 + ch) = *(const uint4*)&T[n][ch];
    }
}

// ---------------------------------------------------------------------------
// QKV GEMM (unchanged R6 form): bf16 MFMA 16x16x32, 128x128 tile, BK=64,
// global_load_lds staging with 8-slot XOR swizzle.  3 blocks/CU.
// z=0/1 -> Q/K bf16 [b,h,s,hd]; z=2 -> V bf16 transposed [b,h,hd,s].
// ---------------------------------------------------------------------------
__global__ __launch_bounds__(256, 3)
void qkv_gemm_mfma(const u16* __restrict__ Xb, const u16* __restrict__ Wt,
                   const float* __restrict__ bq, const float* __restrict__ bk,
                   const float* __restrict__ bv,
                   u16* __restrict__ Qb, u16* __restrict__ Kb,
                   u16* __restrict__ Vt)
{
    const int z = blockIdx.z;
    const u16* W = Wt + (size_t)z * CD * CD;
    const float* bias = (z == 0) ? bq : (z == 1) ? bk : bv;
    const float bscale = (z == 0) ? QSCALE : 1.0f;

    __shared__ u16 smem[16384];         // As [128][64] + Bs [128][64] = 32 KB
    u16* As = smem;
    u16* Bs = smem + 8192;

    const int tid  = threadIdx.x;
    const int w    = tid >> 6;
    const int l    = tid & 63;
    const int l15  = l & 15;
    const int quad = l >> 4;
    const int wm   = w >> 1;
    const int wn   = w & 1;

    const int row0 = blockIdx.x << 7;
    const int n0   = blockIdx.y << 7;

    f32x4 acc[4][4];
    #pragma unroll
    for (int mi = 0; mi < 4; ++mi)
        #pragma unroll
        for (int nt = 0; nt < 4; ++nt)
            acc[mi][nt] = (f32x4){0.f, 0.f, 0.f, 0.f};

    const u16* Ag = Xb + (size_t)row0 * CD;
    const u16* Bg = W  + (size_t)n0   * CD;
    const int lr8 = l >> 3;                 // row within 8-row group
    const int ls  = l & 7;                  // stored slot
    const int lg  = (ls ^ lr8) << 3;        // swizzled global chunk (u16)
    const int q7  = l15 & 7;

    for (int k0 = 0; k0 < CD; k0 += 64) {
        __syncthreads();
        #pragma unroll
        for (int i = 0; i < 4; ++i) {
            int r = w * 32 + 8 * i + lr8;
            load_lds16(Ag + (size_t)r * CD + k0 + lg, As + (size_t)(w * 32 + 8 * i) * 64);
            load_lds16(Bg + (size_t)r * CD + k0 + lg, Bs + (size_t)(w * 32 + 8 * i) * 64);
        }
        __syncthreads();

        #pragma unroll
        for (int kk = 0; kk < 2; ++kk) {
            bf16x8 af[4], bfr[4];
            #pragma unroll
            for (int mi = 0; mi < 4; ++mi)
                af[mi] = *(const bf16x8*)
                    &As[(wm * 64 + mi * 16 + l15) * 64 + (((kk * 4 + quad) ^ q7) << 3)];
            #pragma unroll
            for (int nt = 0; nt < 4; ++nt)
                bfr[nt] = *(const bf16x8*)
                    &Bs[(wn * 64 + nt * 16 + l15) * 64 + (((kk * 4 + quad) ^ q7) << 3)];
            #pragma unroll
            for (int mi = 0; mi < 4; ++mi)
                #pragma unroll
                for (int nt = 0; nt < 4; ++nt)
                    acc[mi][nt] = __builtin_amdgcn_mfma_f32_16x16x32_bf16(
                        af[mi], bfr[nt], acc[mi][nt], 0, 0, 0);
        }
    }

    __syncthreads();   // K-loop LDS reads done; smem reusable

    if (z < 2) {
        u16* Og = (z == 0) ? Qb : Kb;
        float bb[4];
        #pragma unroll
        for (int nt = 0; nt < 4; ++nt)
            bb[nt] = bias[n0 + wn * 64 + nt * 16 + l15] * bscale;

        u16 (*Ct)[136] = (u16(*)[136])smem;
        #pragma unroll
        for (int mh = 0; mh < 2; ++mh) {
            if (wm == mh) {
                #pragma unroll
                for (int nt = 0; nt < 4; ++nt)
                    #pragma unroll
                    for (int mi = 0; mi < 4; ++mi)
                        #pragma unroll
                        for (int r = 0; r < 4; ++r)
                            Ct[mi * 16 + quad * 4 + r][wn * 64 + nt * 16 + l15] =
                                f2bf(acc[mi][nt][r] + bb[nt]);
            }
            __syncthreads();
            #pragma unroll
            for (int it = 0; it < 4; ++it) {
                int c  = tid + (it << 8);
                int rl = c >> 4;
                int ck = c & 15;
                uint4 d = *(const uint4*)&Ct[rl][ck * 8];
                int gcol = n0 + ck * 8;
                int h = gcol >> 6, hd = gcol & 63;
                int m = row0 + mh * 64 + rl;
                int b = m >> 11, s = m & (CS - 1);
                *(uint4*)(Og + ((size_t)(b * CH + h) * CS + s) * CHD + hd) = d;
            }
            __syncthreads();
        }
    } else {
        u16 (*Ct)[136] = (u16(*)[136])smem;
        #pragma unroll
        for (int nh = 0; nh < 2; ++nh) {
            if (wn == nh) {
                #pragma unroll
                for (int nt = 0; nt < 4; ++nt) {
                    int col = n0 + nh * 64 + nt * 16 + l15;
                    float bb = bias[col];
                    #pragma unroll
                    for (int mi = 0; mi < 4; ++mi)
                        #pragma unroll
                        for (int r = 0; r < 4; ++r) {
                            int ml = wm * 64 + mi * 16 + quad * 4 + r;
                            Ct[nt * 16 + l15][ml] = f2bf(acc[mi][nt][r] + bb);
                        }
                }
            }
            __syncthreads();
            #pragma unroll
            for (int it = 0; it < 4; ++it) {
                int c   = tid + (it << 8);
                int dvl = c >> 4;
                int ch  = c & 15;
                uint4 vdat = *(const uint4*)&Ct[dvl][ch * 8];
                int col = n0 + nh * 64 + dvl;
                int h   = col >> 6;
                int dv  = col & 63;
                int m0  = row0 + ch * 8;
                int b   = m0 >> 11;
                int s0  = m0 & (CS - 1);
                *(uint4*)(Vt + (((size_t)(b * CH + h)) * CHD + dv) * CS + s0) = vdat;
            }
            __syncthreads();
        }
    }
}

// ---------------------------------------------------------------------------
// Flash attention v10 = v9 structure with the register cap released.
// v9's __launch_bounds__(512,4) capped VGPRs at 128 while live demand is
// ~140 -> massive scratch spill (WRITE_SIZE 151 MB).  (512,2) allows 256;
// demand fits, no spill.  If allocator lands <=128 we get 2 blocks/CU,
// else 1 block/CU -- latency is hidden by the K/V double-buffer prefetch
// (stage t+1 issued before compute of tile t; one barrier per tile).
// 32x32x16 MFMA, swapped QK^T (S^T: col = q = lane&31), softmax fully
// lane-local (static log2-domain bound), PV A-fragments built in-register
// via v_cvt_pk_bf16_f32 + one shfl_xor(32) per dword pair -- P never
// touches LDS.  Mask loads issued before the stage so the compiler's
// vmcnt wait for them leaves the stage DMA in flight (vmcnt FIFO order).
// Bijective XCD swizzle: 64 consecutive blocks (4 heads) per XCD -> K/V
// L2-resident (2 MB < 4 MB).
// ---------------------------------------------------------------------------

#define ATTN_MLOAD(KT)                                                        \
    f32x4 mv[8];                                                              \
    _Pragma("unroll")                                                         \
    for (int st = 0; st < 2; ++st)                                            \
        _Pragma("unroll")                                                     \
        for (int g = 0; g < 4; ++g)                                           \
            mv[st * 4 + g] = *(const f32x4*)(mrh + ((KT) << 6) + st * 32 +    \
                                             g * 8 + hi * 4);

#define ATTN_STAGE(KT, KD, VD)                                                \
    {                                                                         \
        const int k0s = (KT) << 6;                                            \
        _Pragma("unroll")                                                     \
        for (int i = 0; i < 2; ++i) {                                         \
            const int rl = (qh << 4) + (i << 3);                              \
            load_lds16(Kph + (size_t)(k0s + rl + lr8) * CHD + lg, (KD) + rl * 64); \
            load_lds16(Vph + (size_t)(rl + lr8) * CS + k0s + lg,  (VD) + rl * 64); \
        }                                                                     \
    }

#define ATTN_TILE(KC, VC)                                                     \
    {                                                                         \
        _Pragma("unroll")                                                     \
        for (int st = 0; st < 2; ++st) {                                      \
            bf16x8 kf[4];                                                     \
            _Pragma("unroll")                                                 \
            for (int c = 0; c < 4; ++c)                                       \
                kf[c] = *(const bf16x8*)&(KC)[(st * 32 + l31) * 64 +          \
                            ((((c << 1) + hi) ^ sw7) << 3)];                  \
            f32x16 s;                                                         \
            _Pragma("unroll")                                                 \
            for (int g = 0; g < 4; ++g)                                       \
                _Pragma("unroll")                                             \
                for (int j = 0; j < 4; ++j)                                   \
                    s[g * 4 + j] = fmaf(mv[st * 4 + g][j], LOG2E, -BLOG);     \
            _Pragma("unroll")                                                 \
            for (int c = 0; c < 4; ++c)                                       \
                s = __builtin_amdgcn_mfma_f32_32x32x16_bf16(kf[c], qf[c], s,  \
                                                            0, 0, 0);         \
            _Pragma("unroll")                                                 \
            for (int r = 0; r < 16; ++r) s[r] = exp2f(s[r]);                  \
            lsum += ((s[0] + s[1]) + (s[2] + s[3])) +                         \
                    ((s[4] + s[5]) + (s[6] + s[7])) +                         \
                    ((s[8] + s[9]) + (s[10] + s[11])) +                       \
                    ((s[12] + s[13]) + (s[14] + s[15]));                      \
            _Pragma("unroll")                                                 \
            for (int cc = 0; cc < 2; ++cc) {                                  \
                unsigned px  = cvt_pk_bf16(s[8 * cc + 0], s[8 * cc + 1]);     \
                unsigned px2 = cvt_pk_bf16(s[8 * cc + 2], s[8 * cc + 3]);     \
                unsigned py  = cvt_pk_bf16(s[8 * cc + 4], s[8 * cc + 5]);     \
                unsigned py2 = cvt_pk_bf16(s[8 * cc + 6], s[8 * cc + 7]);     \
                unsigned t1  = __shfl_xor(hi ? px : py, 32);                  \
                unsigned t2  = __shfl_xor(hi ? px2 : py2, 32);                \
                union { u32x4 u; bf16x8 v; } pa;                              \
                pa.u[0] = hi ? t1 : px;                                       \
                pa.u[1] = hi ? t2 : px2;                                      \
                pa.u[2] = hi ? py : t1;                                       \
                pa.u[3] = hi ? py2 : t2;                                      \
                const int c = st * 2 + cc;                                    \
                bf16x8 vlo = *(const bf16x8*)&(VC)[l31 * 64 +                 \
                                 ((((c << 1) + hi) ^ sw7) << 3)];             \
                bf16x8 vhi = *(const bf16x8*)&(VC)[(32 + l31) * 64 +          \
                                 ((((c << 1) + hi) ^ sw7) << 3)];             \
                O0 = __builtin_amdgcn_mfma_f32_32x32x16_bf16(pa.v, vlo, O0,   \
                                                             0, 0, 0);        \
                O1 = __builtin_amdgcn_mfma_f32_32x32x16_bf16(pa.v, vhi, O1,   \
                                                             0, 0, 0);        \
            }                                                                 \
        }                                                                     \
    }

__global__ __launch_bounds__(512, 2)
void attn_mfma(const u16* __restrict__ Qg, const u16* __restrict__ Kg,
               const u16* __restrict__ Vtg, const float* __restrict__ mask,
               float* __restrict__ out)
{
    __shared__ u16 smem[32768];          // 64 KB

    // bijective XCD swizzle: 64 consecutive blocks (4 heads) per XCD
    const int flat = blockIdx.y * 16 + blockIdx.x;      // 512 blocks
    const int nf   = ((flat & 7) << 6) + (flat >> 3);
    const int q0   = (nf & 15) << 7;
    const int bh   = nf >> 4;
    const int b    = bh >> 4;
    const int h    = bh & 15;

    const int tid = threadIdx.x;
    const int w   = tid >> 6;            // 0..7
    const int qh  = w & 3;               // q-group (32 q)
    const int kh  = w >> 2;              // key half (1024 keys)
    const int l   = tid & 63;
    const int l31 = l & 31;
    const int hi  = l >> 5;
    const int lr8 = l >> 3;
    const int lg  = ((l & 7) ^ lr8) << 3;
    const int sw7 = l31 & 7;

    const u16* Qp    = Qg  + (size_t)bh * CS * CHD;
    const u16* Kph   = Kg  + ((size_t)bh * CS + (kh << 10)) * CHD;
    const u16* Vph   = Vtg + (size_t)bh * CHD * CS + (kh << 10);
    const float* mrh = mask + (size_t)b * CS + (kh << 10);

    // LDS: K dbuf [kh][2][64*64], V dbuf [kh][2][64*64]
    u16* K0 = smem + (kh << 13);
    u16* K1 = K0 + 4096;
    u16* V0 = smem + 16384 + (kh << 13);
    u16* V1 = V0 + 4096;

    // Q B-fragments (col = q = lane&31, 8 d-elems at hi*8 per 16-d chunk)
    bf16x8 qf[4];
    #pragma unroll
    for (int c = 0; c < 4; ++c)
        qf[c] = *(const bf16x8*)(
            Qp + (size_t)(q0 + qh * 32 + l31) * CHD + c * 16 + hi * 8);

    f32x16 O0, O1;
    #pragma unroll
    for (int r = 0; r < 16; ++r) { O0[r] = 0.f; O1[r] = 0.f; }
    float lsum = 0.f;

    ATTN_STAGE(0, K0, V0);
    __syncthreads();

    #pragma unroll 1
    for (int kt = 0; kt < 16; kt += 2) {
        {
            ATTN_MLOAD(kt);
            __builtin_amdgcn_sched_barrier(0);
            ATTN_STAGE(kt + 1, K1, V1);
            __builtin_amdgcn_sched_barrier(0);
            ATTN_TILE(K0, V0);
            __syncthreads();
        }
        {
            ATTN_MLOAD(kt + 1);
            __builtin_amdgcn_sched_barrier(0);
            if (kt + 2 < 16) ATTN_STAGE(kt + 2, K0, V0);
            __builtin_amdgcn_sched_barrier(0);
            ATTN_TILE(K1, V1);
            __syncthreads();
        }
    }

    // ---- combine k-halves (linear: static bound) ----
    const float lsf = lsum + __shfl_xor(lsum, 32);

    float* ob   = (float*)smem;               // 32 KB: [4 qh][32 q][64 dv]
    float* lbuf = (float*)(smem + 16384);     // 128 floats (V region dead)

    if (kh == 1) {
        float* obw = ob + (qh << 11);
        #pragma unroll
        for (int r = 0; r < 16; ++r) {
            const int ql = (r & 3) + ((r >> 2) << 3) + (hi << 2);
            obw[ql * 64 + l31]      = O0[r];
            obw[ql * 64 + 32 + l31] = O1[r];
        }
        if (hi == 0) lbuf[(qh << 5) + l31] = lsf;
    }
    __syncthreads();

    if (kh == 0) {
        const float inv = 1.0f / (lsf + lbuf[(qh << 5) + l31]);
        const float* obw = ob + (qh << 11);
        #pragma unroll
        for (int r = 0; r < 16; ++r) {
            const int ql   = (r & 3) + ((r >> 2) << 3) + (hi << 2);
            const float iv = __shfl(inv, ql);
            float* orow = out + ((size_t)b * CS + q0 + (qh << 5) + ql) * CD + h * CHD;
            orow[l31]      = (O0[r] + obw[ql * 64 + l31]) * iv;
            orow[32 + l31] = (O1[r] + obw[ql * 64 + 32 + l31]) * iv;
        }
    }
}

// ---------------------------------------------------------------------------
extern "C" void kernel_launch(void* const* d_in, const int* in_sizes, int n_in,
                              void* d_out, int out_size, void* d_ws, size_t ws_size,
                              hipStream_t stream)
{
    const float* X    = (const float*)d_in[0];
    const float* mask = (const float*)d_in[1];
    const float* Wq   = (const float*)d_in[2];
    const float* bq   = (const float*)d_in[3];
    const float* Wk   = (const float*)d_in[4];
    const float* bk   = (const float*)d_in[5];
    const float* Wv   = (const float*)d_in[6];
    const float* bv   = (const float*)d_in[7];
    float* out = (float*)d_out;

    char* ws = (char*)d_ws;
    u16* Xb = (u16*)(ws);
    u16* Wt = (u16*)(ws + ((size_t)8  << 20));
    u16* Qb = (u16*)(ws + ((size_t)14 << 20));
    u16* Kb = (u16*)(ws + ((size_t)22 << 20));
    u16* Vt = (u16*)(ws + ((size_t)30 << 20));

    convert_x<<<CM * CD / (256 * 8), 256, 0, stream>>>(X, Xb);
    convert_wt<<<dim3(16, 16, 3), 256, 0, stream>>>(Wq, Wk, Wv, Wt);
    qkv_gemm_mfma<<<dim3(CM / 128, CD / 128, 3), 256, 0, stream>>>(
        Xb, Wt, bq, bk, bv, Qb, Kb, Vt);
    attn_mfma<<<dim3(CS / 128, CB * CH), 512, 0, stream>>>(Qb, Kb, Vt, mask, out);
}